// Round 10
// baseline (26211.328 us; speedup 1.0000x reference)
//
#include <hip/hip_runtime.h>
#include <hip/hip_bf16.h>

#define TT 8192
#define BB 16
#define HH 256
#define GG 8       // blocks per layer (16 total)
#define NKS0 9     // K=288: x 0..6, zeros 7..31, h 32..287
#define NKS1 16    // K=512: y0 0..255, h1 256..511
#define ROW0 320   // u16 per batch-row in L0 LDS tile (40 chunks)
#define ROW1 512   // 64 chunks
#define RING0 8    // y0/h0 ring depth
#define RING1 4    // h1 ring depth

typedef unsigned short u16;
typedef unsigned int   u32;
typedef unsigned long long u64;
typedef __attribute__((ext_vector_type(4))) float f32x4;
typedef __attribute__((ext_vector_type(8))) short bf16x8;

union U16X8 { uint4 u; bf16x8 s; };

// ---------------- workspace layout (bytes) ----------------
static const size_t OFF_SLOT = 0;        // u32[16]: 0..7 L0 counters, 8..15 L1
static const size_t OFF_H0   = 1024;     // u32[RING0][2048] = 64 KB  [slot][g][b][16]
static const size_t OFF_H1   = 66560;    // u32[RING1][2048] = 32 KB
static const size_t OFF_A0   = 99328;    // 294912 u16 A-frags L0 (memset bound)
static const size_t OFF_A1   = 689152;   // 524288 u16 A-frags L1
static const size_t OFF_Y1   = 1737728;  // [8192][16][128] u32 y1 history 64 MB

__device__ __forceinline__ float blo(u32 u){ return __uint_as_float(u << 16); }
__device__ __forceinline__ float bhi(u32 u){ return __uint_as_float(u & 0xffff0000u); }
__device__ __forceinline__ float sigf(float x){ return 1.0f/(1.0f + __expf(-x)); }
__device__ __forceinline__ float tanhf_(float x){ return 1.0f - 2.0f/(__expf(2.0f*x) + 1.0f); }
__device__ __forceinline__ u16 f2bf(float v){
  union { __hip_bfloat16 b; u16 s; } u; u.b = __float2bfloat16(v); return u.s;
}
__device__ __forceinline__ u32 ld_slot(const u32* p) {
  return __hip_atomic_load(p, __ATOMIC_RELAXED, __HIP_MEMORY_SCOPE_AGENT);
}
__device__ __forceinline__ u64 ld_d2(const u32* p) {   // 8B exchange read @ LLC
  return __hip_atomic_load((const u64*)p, __ATOMIC_RELAXED, __HIP_MEMORY_SCOPE_AGENT);
}
__device__ __forceinline__ void st_d(u32* p, u32 v) {  // 4B exchange write @ LLC
  __hip_atomic_store(p, v, __ATOMIC_RELAXED, __HIP_MEMORY_SCOPE_AGENT);
}
__device__ __forceinline__ uint4 mk4(u64 a, u64 b) {
  return make_uint4((u32)a, (u32)(a >> 32), (u32)b, (u32)(b >> 32));
}

// A-fragments: [g][wq][rt][ks][lane][8]; row = wq*256 + g*32 + rt*16 + (lane&15),
// k = ks*32 + (lane>>4)*8 + e.  (verbatim r5)
__global__ __launch_bounds__(256) void pack_frags(
    const float* __restrict__ Wih0, const float* __restrict__ Whh0,
    const float* __restrict__ Wih1, const float* __restrict__ Whh1,
    u16* __restrict__ a0, u16* __restrict__ a1) {
  int idx = blockIdx.x*256 + threadIdx.x;
  const int N0 = GG*4*2*NKS0*512;   // 294912
  const int N1 = GG*4*2*NKS1*512;   // 524288
  if (idx < N0) {
    int i = idx;
    int ii = i & 511; int lane = ii >> 3; int e = ii & 7;
    int f = i >> 9; int ks = f % NKS0; f /= NKS0;
    int rt = f & 1; f >>= 1; int wq = f & 3; int g = f >> 2;
    int row = wq*256 + g*32 + rt*16 + (lane & 15);
    int k = ks*32 + (lane >> 4)*8 + e;
    float v = 0.0f;
    if (k < 7)                   v = Wih0[row*7 + k];
    else if (k >= 32 && k < 288) v = Whh0[row*256 + (k - 32)];
    a0[i] = f2bf(v);
  } else if (idx < N0 + N1) {
    int i = idx - N0;
    int ii = i & 511; int lane = ii >> 3; int e = ii & 7;
    int f = i >> 9; int ks = f & 15; f >>= 4;
    int rt = f & 1; f >>= 1; int wq = f & 3; int g = f >> 2;
    int row = wq*256 + g*32 + rt*16 + (lane & 15);
    int k = ks*32 + (lane >> 4)*8 + e;
    float v = (k < 256) ? Wih1[row*256 + k] : Whh1[row*256 + (k - 256)];
    a1[i] = f2bf(v);
  }
}

// Arrive (r5-verbatim): drain exchange stores, block-sync, publish counter.
__device__ __forceinline__ void arrive(u32* slots_, int idx, int r, int tid) {
  asm volatile("s_waitcnt vmcnt(0)" ::: "memory");
  __syncthreads();
  if (tid == 0) st_d(&slots_[idx], (u32)(r + 1));
}

// Fused 2-layer gang, decoupled per-layer barriers. Blocks 0..7 L0, 8..15 L1.
__global__ __launch_bounds__(256, 1) void gangs(
    const float* __restrict__ x,
    const u16* __restrict__ a0, const u16* __restrict__ a1,
    const float* __restrict__ b0, const float* __restrict__ b1,
    u32* __restrict__ h0c, u32* __restrict__ h1c,
    u32* __restrict__ slots_, u32* __restrict__ y1ws,
    float* __restrict__ dout) {
  const int gb = blockIdx.x, tid = threadIdx.x;
  const int l = tid & 63, wq = tid >> 6;
  const int bb_ = l & 15, cq = l >> 4;
  const int pb = tid >> 4, pu = tid & 15;   // pointwise: batch, unit-pair
  __shared__ __align__(16) u16 hlds[16*ROW1];
  __shared__ float pre[4][32][17];
  uint4* lds4 = (uint4*)hlds;
  int budget = 4000000;
  float cst[2] = {0.f, 0.f}, hl[2] = {0.f, 0.f};

  if (gb < GG) {   // ================= LAYER 0 =================
    const int g = gb;
    uint4 A[2][NKS0];
    #pragma unroll
    for (int rt = 0; rt < 2; ++rt)
      #pragma unroll
      for (int ks = 0; ks < NKS0; ++ks)
        A[rt][ks] = ((const uint4*)a0)[ (((g*4 + wq)*2 + rt)*NKS0 + ks)*64 + l ];
    float bias4[2][4];
    #pragma unroll
    for (int rt = 0; rt < 2; ++rt)
      #pragma unroll
      for (int i = 0; i < 4; ++i)
        bias4[rt][i] = b0[wq*256 + g*32 + rt*16 + cq*4 + i];
    const int xb = tid >> 3, xj = tid & 7;
    const int s = tid >> 5, j = tid & 31;       // staging: source block, sub
    for (int z = tid; z < 16*ROW0/2; z += 256) ((u32*)hlds)[z] = 0;
    __syncthreads();

    for (int r = 0; r < TT; ++r) {
      float xv = 0.0f;
      if (tid < 128 && xj < 7)
        xv = x[(size_t)xb*(TT*7) + (size_t)r*7 + xj];

      // wait for producer slot s to publish h0(r-1), then load my 32B slice
      if (r > 0) {
        while (ld_slot(&slots_[s]) < (u32)r) { if (--budget <= 0) break; }
      }
      const u32* bp = h0c + ((r + RING0 - 1) & (RING0-1))*2048
                          + s*256 + (j >> 1)*16 + (j & 1)*8;
      u64 d0 = ld_d2(bp), d1 = ld_d2(bp + 2), d2 = ld_d2(bp + 4), d3 = ld_d2(bp + 6);
      // backpressure: ring slot r&7 about to be overwritten; L1 must have read it
      if (r >= RING0 && tid < 8) {
        while (ld_slot(&slots_[8 + tid]) < (u32)(r - (RING0-1))) { if (--budget <= 0) break; }
      }
      if (tid < 128 && xj < 7)
        hlds[xb*ROW0 + ((xb & 7)*8) + xj] = f2bf(xv);   // chunk 0 ^ (b&7)
      {
        const int b = j >> 1, m = s*4 + (j & 1)*2;
        lds4[b*40 + ((4 + m)     ^ (b & 7))] = mk4(d0, d1);
        lds4[b*40 + ((4 + m + 1) ^ (b & 7))] = mk4(d2, d3);
      }
      __syncthreads();

      f32x4 acc[2];
      #pragma unroll
      for (int rt = 0; rt < 2; ++rt)
        acc[rt] = (f32x4){bias4[rt][0], bias4[rt][1], bias4[rt][2], bias4[rt][3]};
      #pragma unroll
      for (int ks = 0; ks < NKS0; ++ks) {
        U16X8 bfr; bfr.u = lds4[bb_*40 + ((ks*4 + cq) ^ (bb_ & 7))];
        U16X8 afr0; afr0.u = A[0][ks];
        U16X8 afr1; afr1.u = A[1][ks];
        acc[0] = __builtin_amdgcn_mfma_f32_16x16x32_bf16(afr0.s, bfr.s, acc[0], 0, 0, 0);
        acc[1] = __builtin_amdgcn_mfma_f32_16x16x32_bf16(afr1.s, bfr.s, acc[1], 0, 0, 0);
      }
      #pragma unroll
      for (int rt = 0; rt < 2; ++rt)
        #pragma unroll
        for (int ii = 0; ii < 4; ++ii)
          pre[wq][rt*16 + cq*4 + ii][bb_] = acc[rt][ii];
      __syncthreads();

      u32 packed;
      #pragma unroll
      for (int e = 0; e < 2; ++e) {
        int u = 2*pu + e;
        float pi = pre[0][u][pb], pf = pre[1][u][pb],
              pg = pre[2][u][pb], po = pre[3][u][pb];
        cst[e] = sigf(pf)*cst[e] + sigf(pi)*tanhf_(pg);
        hl[e]  = sigf(po)*tanhf_(cst[e]);
      }
      packed = (u32)f2bf(hl[0]) | ((u32)f2bf(hl[1]) << 16);
      st_d(&h0c[(r & (RING0-1))*2048 + g*256 + pb*16 + pu], packed);
      arrive(slots_, g, r, tid);
    }
    #pragma unroll
    for (int e = 0; e < 2; ++e) {
      dout[917504 + pb*256 + g*32 + 2*pu + e] = hl[e];   // h_n[0]
      dout[925696 + pb*256 + g*32 + 2*pu + e] = cst[e];  // c_n[0]
    }
  } else {         // ================= LAYER 1 =================
    const int g = gb - GG;
    uint4 A[2][NKS1];
    #pragma unroll
    for (int rt = 0; rt < 2; ++rt)
      #pragma unroll
      for (int ks = 0; ks < NKS1; ++ks)
        A[rt][ks] = ((const uint4*)a1)[ (((g*4 + wq)*2 + rt)*NKS1 + ks)*64 + l ];
    float bias4[2][4];
    #pragma unroll
    for (int rt = 0; rt < 2; ++rt)
      #pragma unroll
      for (int i = 0; i < 4; ++i)
        bias4[rt][i] = b1[wq*256 + g*32 + rt*16 + cq*4 + i];
    const int hsel = (tid < 128) ? 0 : 1;             // 0: y0 source, 1: h1 source
    const int tt = tid & 127, s = tt >> 4, j = tt & 15;
    __syncthreads();

    for (int t1 = 0; t1 < TT; ++t1) {
      // poll my producer, then load my 64B slice
      if (hsel == 0) {
        while (ld_slot(&slots_[s]) < (u32)(t1 + 1)) { if (--budget <= 0) break; }
      } else if (t1 > 0) {
        while (ld_slot(&slots_[8 + s]) < (u32)t1) { if (--budget <= 0) break; }
      }
      const u32* bp = (hsel == 0)
        ? h0c + (t1 & (RING0-1))*2048 + s*256 + j*16
        : h1c + ((t1 + RING1 - 1) & (RING1-1))*2048 + s*256 + j*16;
      u64 d[8];
      #pragma unroll
      for (int m = 0; m < 8; ++m) d[m] = ld_d2(bp + 2*m);
      {
        const int cb = hsel*32 + s*4;
        #pragma unroll
        for (int c = 0; c < 4; ++c)
          lds4[j*64 + ((cb + c) ^ (j & 7))] = mk4(d[2*c], d[2*c+1]);
      }
      __syncthreads();

      f32x4 acc[2];
      #pragma unroll
      for (int rt = 0; rt < 2; ++rt)
        acc[rt] = (f32x4){bias4[rt][0], bias4[rt][1], bias4[rt][2], bias4[rt][3]};
      #pragma unroll
      for (int ks = 0; ks < NKS1; ++ks) {
        U16X8 bfr; bfr.u = lds4[bb_*64 + ((ks*4 + cq) ^ (bb_ & 7))];
        U16X8 afr0; afr0.u = A[0][ks];
        U16X8 afr1; afr1.u = A[1][ks];
        acc[0] = __builtin_amdgcn_mfma_f32_16x16x32_bf16(afr0.s, bfr.s, acc[0], 0, 0, 0);
        acc[1] = __builtin_amdgcn_mfma_f32_16x16x32_bf16(afr1.s, bfr.s, acc[1], 0, 0, 0);
      }
      #pragma unroll
      for (int rt = 0; rt < 2; ++rt)
        #pragma unroll
        for (int ii = 0; ii < 4; ++ii)
          pre[wq][rt*16 + cq*4 + ii][bb_] = acc[rt][ii];
      __syncthreads();

      u32 packed;
      #pragma unroll
      for (int e = 0; e < 2; ++e) {
        int u = 2*pu + e;
        float pi = pre[0][u][pb], pf = pre[1][u][pb],
              pg = pre[2][u][pb], po = pre[3][u][pb];
        cst[e] = sigf(pf)*cst[e] + sigf(pi)*tanhf_(pg);
        hl[e]  = sigf(po)*tanhf_(cst[e]);
      }
      packed = (u32)f2bf(hl[0]) | ((u32)f2bf(hl[1]) << 16);
      st_d(&h1c[(t1 & (RING1-1))*2048 + g*256 + pb*16 + pu], packed);
      y1ws[(size_t)t1*2048 + pb*128 + g*16 + pu] = packed;   // plain store for head
      arrive(slots_, 8 + g, t1, tid);
    }
    #pragma unroll
    for (int e = 0; e < 2; ++e) {
      dout[917504 + 4096 + pb*256 + g*32 + 2*pu + e] = hl[e];   // h_n[1]
      dout[925696 + 4096 + pb*256 + g*32 + 2*pu + e] = cst[e];  // c_n[1]
    }
  }
}

// Epilogue head (verbatim r5): out[b][t][:] = y1[t][b][:] @ Whead^T + bhead.
__global__ __launch_bounds__(256) void head_kernel(
    const u16* __restrict__ y1, const float* __restrict__ Wh,
    const float* __restrict__ bh, float* __restrict__ out) {
  __shared__ float wt[256][8];
  const int tid = threadIdx.x;
  for (int idx = tid; idx < 2048; idx += 256) {
    int j = idx >> 3, o = idx & 7;
    wt[j][o] = (o < 7) ? Wh[o*256 + j] : 0.0f;
  }
  __syncthreads();
  const int gidx = blockIdx.x*256 + tid;
  const int t = gidx >> 4, b = gidx & 15;
  const uint4* row = (const uint4*)(y1 + (size_t)t*4096 + b*256);
  float4 a03 = {0,0,0,0}, a47 = {0,0,0,0};
  #pragma unroll 4
  for (int jj = 0; jj < 32; ++jj) {
    uint4 v = row[jj];
    u32 ws_[4] = {v.x, v.y, v.z, v.w};
    #pragma unroll
    for (int m = 0; m < 4; ++m) {
      int j = jj*8 + 2*m;
      float h0 = blo(ws_[m]), h1 = bhi(ws_[m]);
      float4 w00 = *(const float4*)&wt[j][0],   w01 = *(const float4*)&wt[j][4];
      float4 w10 = *(const float4*)&wt[j+1][0], w11 = *(const float4*)&wt[j+1][4];
      a03.x += h0*w00.x; a03.y += h0*w00.y; a03.z += h0*w00.z; a03.w += h0*w00.w;
      a47.x += h0*w01.x; a47.y += h0*w01.y; a47.z += h0*w01.z;
      a03.x += h1*w10.x; a03.y += h1*w10.y; a03.z += h1*w10.z; a03.w += h1*w10.w;
      a47.x += h1*w11.x; a47.y += h1*w11.y; a47.z += h1*w11.z;
    }
  }
  const size_t ob = ((size_t)b*TT + t)*7;
  out[ob+0] = a03.x + bh[0]; out[ob+1] = a03.y + bh[1];
  out[ob+2] = a03.z + bh[2]; out[ob+3] = a03.w + bh[3];
  out[ob+4] = a47.x + bh[4]; out[ob+5] = a47.y + bh[5];
  out[ob+6] = a47.z + bh[6];
}

extern "C" void kernel_launch(void* const* d_in, const int* in_sizes, int n_in,
                              void* d_out, int out_size, void* d_ws, size_t ws_size,
                              hipStream_t stream) {
  const float* x     = (const float*)d_in[0];
  const float* Wih0  = (const float*)d_in[1];
  const float* Whh0  = (const float*)d_in[2];
  const float* b0    = (const float*)d_in[3];
  const float* Wih1  = (const float*)d_in[4];
  const float* Whh1  = (const float*)d_in[5];
  const float* b1    = (const float*)d_in[6];
  const float* Whead = (const float*)d_in[7];
  const float* bhead = (const float*)d_in[8];
  char* ws = (char*)d_ws;
  u32* slots = (u32*)(ws + OFF_SLOT);
  u32* h0c   = (u32*)(ws + OFF_H0);
  u32* h1c   = (u32*)(ws + OFF_H1);
  u16* a0    = (u16*)(ws + OFF_A0);
  u16* a1    = (u16*)(ws + OFF_A1);
  u32* y1ws  = (u32*)(ws + OFF_Y1);
  float* out = (float*)d_out;

  hipMemsetAsync(ws, 0, OFF_A0, stream);   // slots + h rings

  pack_frags<<<3200, 256, 0, stream>>>(Wih0, Whh0, Wih1, Whh1, a0, a1);
  gangs<<<2*GG, 256, 0, stream>>>(x, a0, a1, b0, b1, h0c, h1c, slots, y1ws, out);
  head_kernel<<<(TT*BB)/256, 256, 0, stream>>>((const u16*)y1ws, Whead, bhead, out);
}